// Round 4
// baseline (64.790 us; speedup 1.0000x reference)
//
#include <hip/hip_runtime.h>

// Continuity loss, neighbor=3, X = (8192, 4096) fp32 row-major.
// loss = -(1/R) * sum_{i=1,2} sum_{j=0,1,2} |X[r,c]X[r+i,c+j]| ln|X[r,c]X[r+i,c+j]|
//
// Identity: u=|x|, w=u*log2(u)  ->  |ab| ln|ab| = ln2*(w_a*u_b + u_a*w_b).
// One v_log_f32 per element-slot; 6 pair terms per base element factor into
// sliding column sums Su/Sw over rows r+1, r+2.
//
// R3: 3-deep raw-register prefetch pipeline (latency hiding) -> 29.6 us.
// R4: fuse the final reduction into the partial kernel via the last-block-done
// pattern (threadfence + device-scope atomic counter); counter zeroed by a
// 4-byte hipMemsetAsync each call so every call is self-contained.

constexpr int C  = 4096;
constexpr int CQ = C / 4;   // 1024 quads per row
constexpr int H  = 32;      // base rows per strip
constexpr int NT = 256;
constexpr int PF = 3;       // prefetch depth (raw slots)

__global__ __launch_bounds__(NT) void closs_fused(const float* __restrict__ X,
                                                  float* part, unsigned* counter,
                                                  float* out, int R, double scale) {
    const int cq  = (blockIdx.x & 3) * NT + threadIdx.x;  // 0..1023
    const int r0  = (blockIdx.x >> 2) * H;
    const bool halo = (cq < CQ - 1);
    const size_t col = (size_t)cq << 2;

    float raw[PF][6];
    float u[3][6], w[3][6];

    auto load_row = [&](int rr, float* dst) {
        int rabs = r0 + rr;
        int rcl  = rabs < R ? rabs : R - 1;            // block-uniform clamp, no OOB
        const float* p  = X + (size_t)rcl * C + col;
        *reinterpret_cast<float4*>(dst) = *reinterpret_cast<const float4*>(p);
        const float* ph = halo ? p + 4 : X;            // safe dummy addr for last quad
        float2 h = *reinterpret_cast<const float2*>(ph);
        dst[4] = h.x;
        dst[5] = h.y;
    };

    auto uw_row = [&](const float* src, float* uu, float* ww, bool valid) {
#pragma unroll
        for (int k = 0; k < 6; ++k) {
            float a = fabsf(src[k]);
            if (k >= 4 && !halo) a = 0.0f;
            if (!valid) a = 0.0f;
            uu[k] = a;
            ww[k] = a * __log2f(fmaxf(a, 1e-37f));     // a==0 -> w==0 (correct limit)
        }
    };

    // prologue: rows 0,1 -> u/w bufs; slots then hold rows 2,3,4
    load_row(0, raw[0]);
    load_row(1, raw[1]);
    load_row(2, raw[2]);
    uw_row(raw[0], u[0], w[0], true);
    uw_row(raw[1], u[1], w[1], true);
    load_row(3, raw[0]);
    load_row(4, raw[1]);

    float acc = 0.0f;
#pragma unroll
    for (int rr = 0; rr < H; ++rr) {
        const int i0 = rr % 3, i1 = (rr + 1) % 3, i2 = (rr + 2) % 3;  // static
        uw_row(raw[(rr + 2) % PF], u[i2], w[i2], r0 + rr + 2 < R);
        if (rr + 5 <= H + 1) load_row(rr + 5, raw[(rr + 5) % PF]);

        float csu[6], csw[6];
#pragma unroll
        for (int k = 0; k < 6; ++k) {
            csu[k] = u[i1][k] + u[i2][k];
            csw[k] = w[i1][k] + w[i2][k];
        }
#pragma unroll
        for (int k = 0; k < 4; ++k) {
            float Su = csu[k] + csu[k + 1] + csu[k + 2];
            float Sw = csw[k] + csw[k + 1] + csw[k + 2];
            acc = fmaf(w[i0][k], Su, fmaf(u[i0][k], Sw, acc));
        }
    }

    // block reduction: wave shuffle + LDS across 4 waves
#pragma unroll
    for (int off = 32; off > 0; off >>= 1) acc += __shfl_down(acc, off, 64);
    __shared__ float wsum[NT / 64];
    const int lane = threadIdx.x & 63;
    const int wid  = threadIdx.x >> 6;
    if (lane == 0) wsum[wid] = acc;
    __syncthreads();

    __shared__ bool is_last;
    if (threadIdx.x == 0) {
        float s = 0.0f;
#pragma unroll
        for (int ww = 0; ww < NT / 64; ++ww) s += wsum[ww];
        part[blockIdx.x] = s;
        __threadfence();                               // publish partial (device scope)
        unsigned prev = atomicAdd(counter, 1u);        // device-scope atomic
        is_last = (prev == gridDim.x - 1);
    }
    __syncthreads();                                   // is_last is block-uniform

    if (is_last) {
        __threadfence();                               // acquire: see all partials
        const int n = (int)gridDim.x;
        double s = 0.0;
        for (int i = threadIdx.x; i < n; i += NT)
            s += (double)((volatile float*)part)[i];
#pragma unroll
        for (int off = 32; off > 0; off >>= 1) s += __shfl_down(s, off, 64);
        __shared__ double wd[NT / 64];
        if (lane == 0) wd[wid] = s;
        __syncthreads();
        if (threadIdx.x == 0) {
            double t = 0.0;
#pragma unroll
            for (int ww = 0; ww < NT / 64; ++ww) t += wd[ww];
            out[0] = (float)(t * scale);
        }
    }
}

extern "C" void kernel_launch(void* const* d_in, const int* in_sizes, int n_in,
                              void* d_out, int out_size, void* d_ws, size_t ws_size,
                              hipStream_t stream) {
    const float* X = (const float*)d_in[0];
    const int R = in_sizes[0] / C;            // 8192
    const int nblocks = (R / H) * (CQ / NT);  // 256 * 4 = 1024

    float*    part    = (float*)d_ws;                          // nblocks floats
    unsigned* counter = (unsigned*)((char*)d_ws + (size_t)nblocks * sizeof(float));

    // self-contained call: counter must start at 0 (ws is poisoned, not re-poisoned)
    hipMemsetAsync(counter, 0, sizeof(unsigned), stream);

    const double scale = -0.69314718055994530942 / (double)R;
    closs_fused<<<nblocks, NT, 0, stream>>>(X, part, counter, (float*)d_out, R, scale);
}

// Round 5
// 51.152 us; speedup vs baseline: 1.2666x; 1.2666x over previous
//
#include <hip/hip_runtime.h>

// Continuity loss, neighbor=3, X = (8192, 4096) fp32 row-major.
// loss = -(1/R) * sum_{i=1,2} sum_{j=0,1,2} |X[r,c]X[r+i,c+j]| ln|X[r,c]X[r+i,c+j]|
//
// Identity: u=|x|, w=u*log2(u)  ->  |ab| ln|ab| = ln2*(w_a*u_b + u_a*w_b).
// One v_log_f32 per element-slot; 6 pair terms per base element factor into
// sliding column sums Su/Sw over rows r+1, r+2.
//
// R3: 3-deep raw-register prefetch pipeline (latency hiding) -> 29.6 us.
// R4: last-block-done fusion -> 64.8 us REGRESSION (threadfence L2 writeback +
//     compiler killed the register pipeline). Reverted.
// R5: column halo via __shfl_down of the neighbor lane's float4 (2 bpermutes)
//     instead of a per-row float2 VMEM load; only lane 63/wave keeps a
//     predicated 8B load. ~half the VMEM instructions per row-iter.

constexpr int C  = 4096;
constexpr int CQ = C / 4;   // 1024 quads per row
constexpr int H  = 32;      // base rows per strip
constexpr int NT = 256;
constexpr int PF = 3;       // prefetch depth (raw slots)

__global__ __launch_bounds__(NT) void closs_partial(const float* __restrict__ X,
                                                    float* __restrict__ part, int R) {
    const int cq  = (blockIdx.x & 3) * NT + threadIdx.x;  // 0..1023
    const int r0  = (blockIdx.x >> 2) * H;
    const bool halo   = (cq < CQ - 1);                    // cq==1023 has no cols c+4,c+5
    const bool lane63 = ((threadIdx.x & 63) == 63);       // wave-boundary lane
    const size_t col = (size_t)cq << 2;

    float raw[PF][6];
    float u[3][6], w[3][6];

    // unconditional, address-clamped row load; lane63 also fetches its 8B halo
    auto load_row = [&](int rr, float* dst) {
        int rabs = r0 + rr;
        int rcl  = rabs < R ? rabs : R - 1;            // block-uniform clamp, no OOB
        const float* p = X + (size_t)rcl * C + col;
        *reinterpret_cast<float4*>(dst) = *reinterpret_cast<const float4*>(p);
        dst[4] = 0.0f;
        dst[5] = 0.0f;
        if (lane63 && halo) {                          // 1 lane/wave; exec-masked load
            float2 h = *reinterpret_cast<const float2*>(p + 4);
            dst[4] = h.x;
            dst[5] = h.y;
        }
    };

    // fill halo cols 4,5 from lane+1's float4 (lane 63 keeps its loaded/zero values)
    auto finish_halo = [&](float* s) {
        float h4 = __shfl_down(s[0], 1, 64);
        float h5 = __shfl_down(s[1], 1, 64);
        if (!lane63) { s[4] = h4; s[5] = h5; }
    };

    // raw -> (u, w); rows >= R forced to zero (block-uniform `valid`)
    auto uw_row = [&](const float* src, float* uu, float* ww, bool valid) {
#pragma unroll
        for (int k = 0; k < 6; ++k) {
            float a = fabsf(src[k]);
            if (!valid) a = 0.0f;
            uu[k] = a;
            ww[k] = a * __log2f(fmaxf(a, 1e-37f));     // a==0 -> w==0 (correct limit)
        }
    };

    // prologue: rows 0,1 -> u/w bufs; slots then hold rows 2,3,4 in flight
    load_row(0, raw[0]);
    load_row(1, raw[1]);
    load_row(2, raw[2]);
    finish_halo(raw[0]);
    uw_row(raw[0], u[0], w[0], true);                  // r0   < R always
    finish_halo(raw[1]);
    uw_row(raw[1], u[1], w[1], true);                  // r0+1 < R always
    load_row(3, raw[0]);
    load_row(4, raw[1]);

    float acc = 0.0f;
#pragma unroll
    for (int rr = 0; rr < H; ++rr) {
        const int i0 = rr % 3, i1 = (rr + 1) % 3, i2 = (rr + 2) % 3;  // static
        // consume oldest in-flight row (rr+2), then refill its slot with rr+5
        float* s = raw[(rr + 2) % PF];
        finish_halo(s);
        uw_row(s, u[i2], w[i2], r0 + rr + 2 < R);
        if (rr + 5 <= H + 1) load_row(rr + 5, raw[(rr + 5) % PF]);

        float csu[6], csw[6];
#pragma unroll
        for (int k = 0; k < 6; ++k) {
            csu[k] = u[i1][k] + u[i2][k];
            csw[k] = w[i1][k] + w[i2][k];
        }
#pragma unroll
        for (int k = 0; k < 4; ++k) {
            float Su = csu[k] + csu[k + 1] + csu[k + 2];
            float Sw = csw[k] + csw[k + 1] + csw[k + 2];
            acc = fmaf(w[i0][k], Su, fmaf(u[i0][k], Sw, acc));
        }
    }

    // wave shuffle reduction + LDS across 4 waves
#pragma unroll
    for (int off = 32; off > 0; off >>= 1) acc += __shfl_down(acc, off, 64);
    __shared__ float wsum[NT / 64];
    const int lane = threadIdx.x & 63;
    const int wid  = threadIdx.x >> 6;
    if (lane == 0) wsum[wid] = acc;
    __syncthreads();
    if (threadIdx.x == 0) {
        float s = 0.0f;
#pragma unroll
        for (int ww = 0; ww < NT / 64; ++ww) s += wsum[ww];
        part[blockIdx.x] = s;
    }
}

__global__ __launch_bounds__(256) void closs_final(const float* __restrict__ part,
                                                   float* __restrict__ out, int n,
                                                   double scale) {
    double s = 0.0;
    for (int i = threadIdx.x; i < n; i += 256) s += (double)part[i];
#pragma unroll
    for (int off = 32; off > 0; off >>= 1) s += __shfl_down(s, off, 64);
    __shared__ double wsum[4];
    const int lane = threadIdx.x & 63;
    const int wid  = threadIdx.x >> 6;
    if (lane == 0) wsum[wid] = s;
    __syncthreads();
    if (threadIdx.x == 0) {
        double t = wsum[0] + wsum[1] + wsum[2] + wsum[3];
        out[0] = (float)(t * scale);
    }
}

extern "C" void kernel_launch(void* const* d_in, const int* in_sizes, int n_in,
                              void* d_out, int out_size, void* d_ws, size_t ws_size,
                              hipStream_t stream) {
    const float* X = (const float*)d_in[0];
    const int R = in_sizes[0] / C;            // 8192
    const int nblocks = (R / H) * (CQ / NT);  // 256 * 4 = 1024

    float* part = (float*)d_ws;               // nblocks floats

    closs_partial<<<nblocks, NT, 0, stream>>>(X, part, R);

    const double scale = -0.69314718055994530942 / (double)R;
    closs_final<<<1, 256, 0, stream>>>(part, (float*)d_out, nblocks, scale);
}

// Round 6
// 29.513 us; speedup vs baseline: 2.1953x; 1.7332x over previous
//
#include <hip/hip_runtime.h>

// Continuity loss, neighbor=3, X = (8192, 4096) fp32 row-major.
// loss = -(1/R) * sum_{i=1,2} sum_{j=0,1,2} |X[r,c]X[r+i,c+j]| ln|X[r,c]X[r+i,c+j]|
//
// Identity: u=|x|, w=u*log2(u)  ->  |ab| ln|ab| = ln2*(w_a*u_b + u_a*w_b).
// One v_log_f32 per element-slot; 6 pair terms per base element factor into
// sliding column sums Su/Sw over rows r+1, r+2.
//
// R3: 3-deep raw-register prefetch pipeline (latency hiding) -> 29.6 us.
// R4: last-block-done fusion -> 64.8 us REGRESSION. Reverted.
// R5: shfl-down halo -> 51.2 us REGRESSION (bpermute in critical path). Reverted.
// R6: R3 structure + __launch_bounds__(256, 4): force VGPR <= 128 so 4 waves/SIMD
//     (16 waves/CU, whole grid co-resident). R5 counters showed VGPR=140 ->
//     2 waves/SIMD occupancy cliff (OccupancyPercent ~10, VALUBusy ~20, BW ~11%).

constexpr int C  = 4096;
constexpr int CQ = C / 4;   // 1024 quads per row
constexpr int H  = 32;      // base rows per strip
constexpr int NT = 256;
constexpr int PF = 3;       // prefetch depth (raw slots)

__global__ __launch_bounds__(NT, 4) void closs_partial(const float* __restrict__ X,
                                                       float* __restrict__ part, int R) {
    const int cq  = (blockIdx.x & 3) * NT + threadIdx.x;  // 0..1023
    const int r0  = (blockIdx.x >> 2) * H;
    const bool halo = (cq < CQ - 1);                      // last quad has no cols c+4,c+5
    const size_t col = (size_t)cq << 2;

    float raw[PF][6];
    float u[3][6], w[3][6];

    // unconditional, address-clamped row load into a raw slot
    auto load_row = [&](int rr, float* dst) {
        int rabs = r0 + rr;
        int rcl  = rabs < R ? rabs : R - 1;            // block-uniform clamp, no OOB
        const float* p  = X + (size_t)rcl * C + col;
        *reinterpret_cast<float4*>(dst) = *reinterpret_cast<const float4*>(p);
        const float* ph = halo ? p + 4 : X;            // safe dummy addr for last quad
        float2 h = *reinterpret_cast<const float2*>(ph);
        dst[4] = h.x;
        dst[5] = h.y;
    };

    // raw -> (u, w); invalid rows (>= R) and halo-less lanes forced to zero
    auto uw_row = [&](const float* src, float* uu, float* ww, bool valid) {
#pragma unroll
        for (int k = 0; k < 6; ++k) {
            float a = fabsf(src[k]);
            if (k >= 4 && !halo) a = 0.0f;
            if (!valid) a = 0.0f;
            uu[k] = a;
            ww[k] = a * __log2f(fmaxf(a, 1e-37f));     // a==0 -> w==0 (correct limit)
        }
    };

    // prologue: rows 0,1 -> u/w bufs; slots then hold rows 2,3,4 in flight
    load_row(0, raw[0]);
    load_row(1, raw[1]);
    load_row(2, raw[2]);
    uw_row(raw[0], u[0], w[0], true);   // r0   < R always
    uw_row(raw[1], u[1], w[1], true);   // r0+1 < R always (H >= 2)
    load_row(3, raw[0]);
    load_row(4, raw[1]);

    float acc = 0.0f;
#pragma unroll
    for (int rr = 0; rr < H; ++rr) {
        const int i0 = rr % 3, i1 = (rr + 1) % 3, i2 = (rr + 2) % 3;  // static
        // consume oldest in-flight row (rr+2), then refill its slot with rr+5
        uw_row(raw[(rr + 2) % PF], u[i2], w[i2], r0 + rr + 2 < R);
        if (rr + 5 <= H + 1) load_row(rr + 5, raw[(rr + 5) % PF]);

        float csu[6], csw[6];
#pragma unroll
        for (int k = 0; k < 6; ++k) {
            csu[k] = u[i1][k] + u[i2][k];
            csw[k] = w[i1][k] + w[i2][k];
        }
#pragma unroll
        for (int k = 0; k < 4; ++k) {
            float Su = csu[k] + csu[k + 1] + csu[k + 2];
            float Sw = csw[k] + csw[k + 1] + csw[k + 2];
            acc = fmaf(w[i0][k], Su, fmaf(u[i0][k], Sw, acc));
        }
    }

    // wave shuffle reduction + LDS across 4 waves
#pragma unroll
    for (int off = 32; off > 0; off >>= 1) acc += __shfl_down(acc, off, 64);
    __shared__ float wsum[NT / 64];
    const int lane = threadIdx.x & 63;
    const int wid  = threadIdx.x >> 6;
    if (lane == 0) wsum[wid] = acc;
    __syncthreads();
    if (threadIdx.x == 0) {
        float s = 0.0f;
#pragma unroll
        for (int ww = 0; ww < NT / 64; ++ww) s += wsum[ww];
        part[blockIdx.x] = s;
    }
}

__global__ __launch_bounds__(256) void closs_final(const float* __restrict__ part,
                                                   float* __restrict__ out, int n,
                                                   double scale) {
    double s = 0.0;
    for (int i = threadIdx.x; i < n; i += 256) s += (double)part[i];
#pragma unroll
    for (int off = 32; off > 0; off >>= 1) s += __shfl_down(s, off, 64);
    __shared__ double wsum[4];
    const int lane = threadIdx.x & 63;
    const int wid  = threadIdx.x >> 6;
    if (lane == 0) wsum[wid] = s;
    __syncthreads();
    if (threadIdx.x == 0) {
        double t = wsum[0] + wsum[1] + wsum[2] + wsum[3];
        out[0] = (float)(t * scale);
    }
}

extern "C" void kernel_launch(void* const* d_in, const int* in_sizes, int n_in,
                              void* d_out, int out_size, void* d_ws, size_t ws_size,
                              hipStream_t stream) {
    const float* X = (const float*)d_in[0];
    const int R = in_sizes[0] / C;            // 8192
    const int nblocks = (R / H) * (CQ / NT);  // 256 * 4 = 1024

    float* part = (float*)d_ws;               // nblocks floats

    closs_partial<<<nblocks, NT, 0, stream>>>(X, part, R);

    const double scale = -0.69314718055994530942 / (double)R;
    closs_final<<<1, 256, 0, stream>>>(part, (float*)d_out, nblocks, scale);
}